// Round 1
// baseline (1252.543 us; speedup 1.0000x reference)
//
#include <hip/hip_runtime.h>
#include <cstdint>
#include <cstddef>

// Problem constants (fixed by the reference)
#define IN_F  4096
#define OUT_F 4096
#define MTOT  16384   // 4 * 4096 rows of x
#define RANK  16

typedef unsigned short u16;
typedef __attribute__((ext_vector_type(8))) short short8;  // 8 x bf16 (4 VGPRs)
typedef __attribute__((ext_vector_type(4))) float f32x4;

// ---- round-to-nearest-even f32 -> bf16 (no NaN inputs in this problem) ----
__device__ __forceinline__ u16 f2bf(float f) {
  union { float f; uint32_t u; } v; v.f = f;
  uint32_t u = v.u;
  return (u16)((u + 0x7fffu + ((u >> 16) & 1u)) >> 16);
}

// ---- async global->LDS, 16 bytes per lane ----
__device__ __forceinline__ void async_copy16(const void* g, void* l) {
  __builtin_amdgcn_global_load_lds(
      (const __attribute__((address_space(1))) unsigned int*)g,
      (__attribute__((address_space(3))) unsigned int*)l,
      16, 0, 0);
}

// =====================  kernel 1: x f32 -> bf16  =====================
// grid: MTOT*IN_F/8/256 = 32768 blocks, each thread converts 8 floats.
__global__ __launch_bounds__(256) void cvt_x_kernel(const float* __restrict__ x,
                                                    u16* __restrict__ xb) {
  int i = blockIdx.x * 256 + threadIdx.x;
  const float4* xp = (const float4*)x;
  float4 a = xp[2 * i];
  float4 c = xp[2 * i + 1];
  union { u16 s[8]; uint4 v; } o;
  o.s[0] = f2bf(a.x); o.s[1] = f2bf(a.y); o.s[2] = f2bf(a.z); o.s[3] = f2bf(a.w);
  o.s[4] = f2bf(c.x); o.s[5] = f2bf(c.y); o.s[6] = f2bf(c.z); o.s[7] = f2bf(c.w);
  ((uint4*)xb)[i] = o.v;
}

// =====================  kernel 2: W_eff = W + B@A -> bf16  =====================
// Each thread: 8 consecutive i of one output row o. Block covers half of one
// o-row => Bm[o*16+r] is wave-uniform (scalar loads). A (256 KB) is L2-resident.
__global__ __launch_bounds__(256) void build_weff_kernel(const float* __restrict__ W,
                                                         const float* __restrict__ A,
                                                         const float* __restrict__ Bm,
                                                         u16* __restrict__ wb) {
  int idx = blockIdx.x * 256 + threadIdx.x;
  int o  = idx >> 9;            // IN_F/8 = 512 threads per row
  int i0 = (idx & 511) << 3;
  const float4* wp = (const float4*)(W + (size_t)o * IN_F + i0);
  float4 a0 = wp[0], a1 = wp[1];
  float acc[8] = {a0.x, a0.y, a0.z, a0.w, a1.x, a1.y, a1.z, a1.w};
#pragma unroll
  for (int r = 0; r < RANK; ++r) {
    float bo = Bm[(size_t)o * RANK + r];
    const float4* ap = (const float4*)(A + (size_t)r * IN_F + i0);
    float4 b0 = ap[0], b1 = ap[1];
    acc[0] += bo * b0.x; acc[1] += bo * b0.y; acc[2] += bo * b0.z; acc[3] += bo * b0.w;
    acc[4] += bo * b1.x; acc[5] += bo * b1.y; acc[6] += bo * b1.z; acc[7] += bo * b1.w;
  }
  union { u16 s[8]; uint4 v; } ov;
#pragma unroll
  for (int j = 0; j < 8; ++j) ov.s[j] = f2bf(acc[j]);
  ((uint4*)wb)[idx] = ov.v;
}

// =====================  kernel 3: bf16 GEMM (m97 structure)  =====================
// C[m][n] = sum_k xb[m][k] * wb[n][k] + bias[n],  output fp32.
// 128x128 tile / block, BK=64, 256 threads = 4 waves in 2x2, each wave 4x4 of
// 16x16x32 MFMA. LDS K-chunks XOR-swizzled by row to kill ds_read_b128 bank
// conflicts (global side of global_load_lds is per-lane addressable, so the
// swizzle is free at staging time).
#define BM 128
#define BN 128
#define BK 64

__global__ __launch_bounds__(256) void gemm_kernel(const u16* __restrict__ xb,
                                                   const u16* __restrict__ wb,
                                                   const float* __restrict__ bias,
                                                   float* __restrict__ out) {
  __shared__ u16 lsA[BM * BK];   // 16 KB
  __shared__ u16 lsB[BN * BK];   // 16 KB

  const int t = threadIdx.x;
  const int bm = blockIdx.y * BM;
  const int bn = blockIdx.x * BN;

  const int w    = t >> 6;
  const int lane = t & 63;
  const int wm = (w >> 1) * 64;   // wave's 64-row quadrant
  const int wn = (w & 1) * 64;    // wave's 64-col quadrant
  const int fr = lane & 15;       // fragment row/col index
  const int fq = lane >> 4;       // quad 0..3

  f32x4 acc[4][4];
#pragma unroll
  for (int i = 0; i < 4; ++i)
#pragma unroll
    for (int j = 0; j < 4; ++j) acc[i][j] = (f32x4)0.0f;

  // staging decomposition: 256 threads x 16 B = 32 rows (of 128 B) per issue
  const int srow = t >> 3;   // 0..31
  const int slc  = t & 7;    // LDS chunk slot within row (8 x 16 B chunks)

  for (int k0 = 0; k0 < IN_F; k0 += BK) {
#pragma unroll
    for (int i = 0; i < 4; ++i) {
      int row = i * 32 + srow;
      int gc  = slc ^ (row & 7);                       // global chunk for this slot
      const u16* ga = xb + ((size_t)(bm + row) * IN_F + k0 + gc * 8);
      async_copy16(ga, &lsA[row * BK + slc * 8]);
      const u16* gb = wb + ((size_t)(bn + row) * IN_F + k0 + gc * 8);
      async_copy16(gb, &lsB[row * BK + slc * 8]);
    }
    __syncthreads();   // compiler drains vmcnt before s_barrier

#pragma unroll
    for (int s = 0; s < 2; ++s) {
      short8 aF[4], bF[4];
#pragma unroll
      for (int tm = 0; tm < 4; ++tm) {
        int m  = wm + tm * 16 + fr;
        int sc = (s * 4 + fq) ^ (m & 7);
        aF[tm] = *(const short8*)&lsA[m * BK + sc * 8];
      }
#pragma unroll
      for (int tn = 0; tn < 4; ++tn) {
        int n  = wn + tn * 16 + fr;
        int sc = (s * 4 + fq) ^ (n & 7);
        bF[tn] = *(const short8*)&lsB[n * BK + sc * 8];
      }
#pragma unroll
      for (int tm = 0; tm < 4; ++tm)
#pragma unroll
        for (int tn = 0; tn < 4; ++tn)
          acc[tm][tn] = __builtin_amdgcn_mfma_f32_16x16x32_bf16(
              aF[tm], bF[tn], acc[tm][tn], 0, 0, 0);
    }
    __syncthreads();
  }

  // Epilogue: C/D layout col = lane&15, row = (lane>>4)*4 + reg  [m89/m91]
#pragma unroll
  for (int tn = 0; tn < 4; ++tn) {
    int n = bn + wn + tn * 16 + fr;
    float bv = bias[n];
#pragma unroll
    for (int tm = 0; tm < 4; ++tm) {
      int m0 = bm + wm + tm * 16 + fq * 4;
      f32x4 v = acc[tm][tn];
#pragma unroll
      for (int r = 0; r < 4; ++r)
        out[(size_t)(m0 + r) * OUT_F + n] = v[r] + bv;
    }
  }
}

// =====================  launch  =====================
extern "C" void kernel_launch(void* const* d_in, const int* in_sizes, int n_in,
                              void* d_out, int out_size, void* d_ws, size_t ws_size,
                              hipStream_t stream) {
  const float* x  = (const float*)d_in[0];   // [4,4096,4096]
  const float* W  = (const float*)d_in[1];   // [4096,4096]
  const float* b  = (const float*)d_in[2];   // [4096]
  const float* A  = (const float*)d_in[3];   // [16,4096]
  const float* Bm = (const float*)d_in[4];   // [4096,16]
  float* out = (float*)d_out;

  // workspace layout: xb (bf16, 128 MB) | wb (bf16, 32 MB)
  u16* xb = (u16*)d_ws;
  u16* wb = (u16*)((char*)d_ws + (size_t)MTOT * IN_F * sizeof(u16));

  cvt_x_kernel<<<(MTOT * IN_F) / 8 / 256, 256, 0, stream>>>(x, xb);
  build_weff_kernel<<<(OUT_F * IN_F) / 8 / 256, 256, 0, stream>>>(W, A, Bm, wb);
  gemm_kernel<<<dim3(OUT_F / BN, MTOT / BM), 256, 0, stream>>>(xb, wb, b, out);
}